// Round 1
// baseline (238.809 us; speedup 1.0000x reference)
//
#include <hip/hip_runtime.h>

typedef unsigned short u16;
typedef unsigned int   u32;
typedef __bf16 bf16x8 __attribute__((ext_vector_type(8)));
typedef float  f32x4  __attribute__((ext_vector_type(4)));

union U16B { int4 i4; bf16x8 b8; u16 u[8]; };

static __device__ __forceinline__ u16 f2b(float f) {
  u32 x = __float_as_uint(f);
  x += 0x7FFFu + ((x >> 16) & 1u);   // RNE (inputs finite, no NaN care)
  return (u16)(x >> 16);
}
static __device__ __forceinline__ float b2f(u16 s) {
  return __uint_as_float(((u32)s) << 16);
}

// ---------------- weight transpose + fp32->bf16 convert ----------------
struct TransA { const float* W[4]; u16* Wt[4]; };

__global__ __launch_bounds__(256) void transW(TransA a) {
  const float* W  = a.W[blockIdx.z];
  u16*         Wt = a.Wt[blockIdx.z];
  __shared__ float t[64][65];
  const int bx = blockIdx.x * 64, by = blockIdx.y * 64;
  const int tx = threadIdx.x & 63, ty = threadIdx.x >> 6;
  #pragma unroll
  for (int j = 0; j < 16; ++j) {
    int row = j * 4 + ty;
    t[row][tx] = W[(size_t)(by + row) * 1024 + bx + tx];
  }
  __syncthreads();
  #pragma unroll
  for (int j = 0; j < 16; ++j) {
    int row = j * 4 + ty;           // Wt[n][k] = W[k][n]
    Wt[(size_t)(bx + row) * 1024 + by + tx] = f2b(t[tx][row]);
  }
}

// ---------------- GEMM: C[M][N] = A[M][K] * Bt[N][K]^T + bias ----------------
// 128x128 tile, BK=64, 256 threads (4 waves, each 64x64 via 4x4 16x16x32 MFMA).
// LDS XOR-swizzled (unit ^= row&7) to avoid 16-way bank conflicts on ds_read_b128.
struct GemmB { const void* A[3]; const u16* Bt[3]; const float* bias[3]; void* C[3]; };

template<bool A_F32, bool OUT_F32>
__global__ __launch_bounds__(256) void gemm_bt(GemmB g) {
  constexpr int K = 1024, N = 1024;
  __shared__ u16 As[128 * 64];
  __shared__ u16 Bs[128 * 64];
  const int z = blockIdx.z;
  const void*  Ap   = g.A[z];
  const u16*   Bt   = g.Bt[z];
  const float* bias = g.bias[z];
  const int tid = threadIdx.x;
  const int row0 = blockIdx.y * 128, col0 = blockIdx.x * 128;
  const int wid = tid >> 6, lane = tid & 63;
  const int wr = wid >> 1, wc = wid & 1;
  const int lo = lane & 15, hi = lane >> 4;
  const int rs = tid >> 3, us = tid & 7;   // staging: row-within-chunk, 16B-unit

  f32x4 acc[4][4];
  const f32x4 z4 = {0.f, 0.f, 0.f, 0.f};
  #pragma unroll
  for (int i = 0; i < 4; ++i)
    #pragma unroll
    for (int j = 0; j < 4; ++j) acc[i][j] = z4;

  for (int kt = 0; kt < K / 64; ++kt) {
    __syncthreads();
    #pragma unroll
    for (int c = 0; c < 4; ++c) {
      int r = c * 32 + rs;
      int lds = r * 64 + ((us ^ (r & 7)) << 3);
      int4 av;
      if (A_F32) {
        const float* s = (const float*)Ap + (size_t)(row0 + r) * K + kt * 64 + us * 8;
        float4 f0 = *(const float4*)s;
        float4 f1 = *(const float4*)(s + 4);
        U16B t;
        t.u[0] = f2b(f0.x); t.u[1] = f2b(f0.y); t.u[2] = f2b(f0.z); t.u[3] = f2b(f0.w);
        t.u[4] = f2b(f1.x); t.u[5] = f2b(f1.y); t.u[6] = f2b(f1.z); t.u[7] = f2b(f1.w);
        av = t.i4;
      } else {
        av = *(const int4*)((const u16*)Ap + (size_t)(row0 + r) * K + kt * 64 + us * 8);
      }
      *(int4*)&As[lds] = av;
      *(int4*)&Bs[lds] = *(const int4*)(Bt + (size_t)(col0 + r) * K + kt * 64 + us * 8);
    }
    __syncthreads();
    #pragma unroll
    for (int ks = 0; ks < 2; ++ks) {
      bf16x8 af[4], bfr[4];
      #pragma unroll
      for (int mf = 0; mf < 4; ++mf) {
        int r = wr * 64 + mf * 16 + lo;
        af[mf] = *(const bf16x8*)&As[r * 64 + (((ks * 4 + hi) ^ (r & 7)) << 3)];
      }
      #pragma unroll
      for (int nf = 0; nf < 4; ++nf) {
        int r = wc * 64 + nf * 16 + lo;
        bfr[nf] = *(const bf16x8*)&Bs[r * 64 + (((ks * 4 + hi) ^ (r & 7)) << 3)];
      }
      #pragma unroll
      for (int mf = 0; mf < 4; ++mf)
        #pragma unroll
        for (int nf = 0; nf < 4; ++nf)
          acc[mf][nf] = __builtin_amdgcn_mfma_f32_16x16x32_bf16(af[mf], bfr[nf], acc[mf][nf], 0, 0, 0);
    }
  }

  #pragma unroll
  for (int nf = 0; nf < 4; ++nf) {
    int col = col0 + wc * 64 + nf * 16 + lo;
    float bv = bias[col];
    #pragma unroll
    for (int mf = 0; mf < 4; ++mf) {
      int rb = row0 + wr * 64 + mf * 16 + hi * 4;   // C/D: row=(l>>4)*4+e, col=l&15
      #pragma unroll
      for (int e = 0; e < 4; ++e) {
        float v = acc[mf][nf][e] + bv;
        if (OUT_F32) ((float*)g.C[z])[(size_t)(rb + e) * N + col] = v;
        else         ((u16*)g.C[z])[(size_t)(rb + e) * N + col] = f2b(v);
      }
    }
  }
}

// ---------------- flash attention ----------------
// Block: 128 q-rows of one (b,h); 4 waves x 32 rows. KBLK=64, 32 k-iters.
// Q pre-scaled by 0.125*log2(e) -> softmax in exp2 domain.
__global__ __launch_bounds__(256) void attn_fwd(const u16* __restrict__ Q,
                                                const u16* __restrict__ Kp,
                                                const u16* __restrict__ Vp,
                                                u16* __restrict__ O) {
  __shared__ u16 Ks[64 * 64];    // K tile  [kk][d]  (swizzled rows)
  __shared__ u16 Vts[64 * 64];   // V^T tile [d][kk] (swizzled rows)
  __shared__ u16 Ps[128 * 64];   // P tile  [q][kk]  (swizzled rows)
  const int tid = threadIdx.x;
  const int qb = blockIdx.x, h = blockIdx.y, b = blockIdx.z;
  const int wid = tid >> 6, lane = tid & 63;
  const int lo = lane & 15, hi = lane >> 4;
  const int rs = tid >> 3, us = tid & 7;
  const int hoff = h * 64;
  const size_t rowQ0 = (size_t)b * 2048 + (size_t)qb * 128;
  const float QSCALE = 0.125f * 1.4426950408889634f;

  // Q fragments in registers, pre-scaled
  bf16x8 qf[2][2];
  #pragma unroll
  for (int mf = 0; mf < 2; ++mf)
    #pragma unroll
    for (int ks = 0; ks < 2; ++ks) {
      size_t r = rowQ0 + wid * 32 + mf * 16 + lo;
      U16B t; t.i4 = *(const int4*)&Q[r * 1024 + hoff + ks * 32 + hi * 8];
      U16B o;
      #pragma unroll
      for (int j = 0; j < 8; ++j) o.u[j] = f2b(b2f(t.u[j]) * QSCALE);
      qf[mf][ks] = o.b8;
    }

  f32x4 oacc[2][4];
  const f32x4 z4 = {0.f, 0.f, 0.f, 0.f};
  float m_r[2][4], l_r[2][4];
  #pragma unroll
  for (int mf = 0; mf < 2; ++mf) {
    #pragma unroll
    for (int df = 0; df < 4; ++df) oacc[mf][df] = z4;
    #pragma unroll
    for (int e = 0; e < 4; ++e) { m_r[mf][e] = -1e30f; l_r[mf][e] = 0.f; }
  }

  for (int kb = 0; kb < 32; ++kb) {
    const int kv0 = kb * 64;
    __syncthreads();
    // stage K (swizzled linear) and V (transposed into Vts, swizzled)
    #pragma unroll
    for (int c = 0; c < 2; ++c) {
      int r = c * 32 + rs;
      size_t go = ((size_t)b * 2048 + kv0 + r) * 1024 + hoff + us * 8;
      *(int4*)&Ks[r * 64 + ((us ^ (r & 7)) << 3)] = *(const int4*)&Kp[go];
      U16B vv; vv.i4 = *(const int4*)&Vp[go];
      #pragma unroll
      for (int j = 0; j < 8; ++j) {
        int d = us * 8 + j;
        Vts[d * 64 + (r ^ ((d & 7) << 3))] = vv.u[j];
      }
    }
    __syncthreads();

    // S = Q K^T  (scores already in log2 domain via Q pre-scale)
    f32x4 sfr[2][4];
    #pragma unroll
    for (int mf = 0; mf < 2; ++mf)
      #pragma unroll
      for (int nf = 0; nf < 4; ++nf) sfr[mf][nf] = z4;
    #pragma unroll
    for (int ks = 0; ks < 2; ++ks) {
      bf16x8 kf[4];
      #pragma unroll
      for (int nf = 0; nf < 4; ++nf) {
        int r = nf * 16 + lo;
        kf[nf] = *(const bf16x8*)&Ks[r * 64 + (((ks * 4 + hi) ^ (r & 7)) << 3)];
      }
      #pragma unroll
      for (int mf = 0; mf < 2; ++mf)
        #pragma unroll
        for (int nf = 0; nf < 4; ++nf)
          sfr[mf][nf] = __builtin_amdgcn_mfma_f32_16x16x32_bf16(qf[mf][ks], kf[nf], sfr[mf][nf], 0, 0, 0);
    }

    // online softmax: rows live on 16-lane groups -> shfl_xor reduce
    #pragma unroll
    for (int mf = 0; mf < 2; ++mf) {
      float pm[4], cc[4], ps[4];
      #pragma unroll
      for (int e = 0; e < 4; ++e)
        pm[e] = fmaxf(fmaxf(sfr[mf][0][e], sfr[mf][1][e]),
                      fmaxf(sfr[mf][2][e], sfr[mf][3][e]));
      #pragma unroll
      for (int st = 1; st < 16; st <<= 1)
        #pragma unroll
        for (int e = 0; e < 4; ++e)
          pm[e] = fmaxf(pm[e], __shfl_xor(pm[e], st));
      #pragma unroll
      for (int e = 0; e < 4; ++e) {
        float mn = fmaxf(m_r[mf][e], pm[e]);
        cc[e] = __builtin_amdgcn_exp2f(m_r[mf][e] - mn);
        m_r[mf][e] = mn;
        l_r[mf][e] *= cc[e];
        ps[e] = 0.f;
      }
      #pragma unroll
      for (int df = 0; df < 4; ++df)
        #pragma unroll
        for (int e = 0; e < 4; ++e)
          oacc[mf][df][e] *= cc[e];
      #pragma unroll
      for (int nf = 0; nf < 4; ++nf) {
        int kk = nf * 16 + lo;
        #pragma unroll
        for (int e = 0; e < 4; ++e) {
          float p = __builtin_amdgcn_exp2f(sfr[mf][nf][e] - m_r[mf][e]);
          ps[e] += p;
          int q = wid * 32 + mf * 16 + hi * 4 + e;
          Ps[q * 64 + (kk ^ ((q & 7) << 3))] = f2b(p);
        }
      }
      #pragma unroll
      for (int st = 1; st < 16; st <<= 1)
        #pragma unroll
        for (int e = 0; e < 4; ++e)
          ps[e] += __shfl_xor(ps[e], st);
      #pragma unroll
      for (int e = 0; e < 4; ++e) l_r[mf][e] += ps[e];
    }
    __syncthreads();

    // O += P V
    #pragma unroll
    for (int ksp = 0; ksp < 2; ++ksp) {
      bf16x8 pa[2], vb[4];
      #pragma unroll
      for (int mf = 0; mf < 2; ++mf) {
        int q = wid * 32 + mf * 16 + lo;
        pa[mf] = *(const bf16x8*)&Ps[q * 64 + (((ksp * 4 + hi) ^ (q & 7)) << 3)];
      }
      #pragma unroll
      for (int df = 0; df < 4; ++df) {
        int d = df * 16 + lo;
        vb[df] = *(const bf16x8*)&Vts[d * 64 + (((ksp * 4 + hi) ^ (d & 7)) << 3)];
      }
      #pragma unroll
      for (int mf = 0; mf < 2; ++mf)
        #pragma unroll
        for (int df = 0; df < 4; ++df)
          oacc[mf][df] = __builtin_amdgcn_mfma_f32_16x16x32_bf16(pa[mf], vb[df], oacc[mf][df], 0, 0, 0);
    }
  }

  // epilogue: normalize and store bf16
  #pragma unroll
  for (int mf = 0; mf < 2; ++mf) {
    float inv[4];
    #pragma unroll
    for (int e = 0; e < 4; ++e) inv[e] = __builtin_amdgcn_rcpf(l_r[mf][e]);
    #pragma unroll
    for (int df = 0; df < 4; ++df)
      #pragma unroll
      for (int e = 0; e < 4; ++e) {
        size_t row = rowQ0 + wid * 32 + mf * 16 + hi * 4 + e;
        O[row * 1024 + hoff + df * 16 + lo] = f2b(oacc[mf][df][e] * inv[e]);
      }
  }
}

// ---------------- launch ----------------
extern "C" void kernel_launch(void* const* d_in, const int* in_sizes, int n_in,
                              void* d_out, int out_size, void* d_ws, size_t ws_size,
                              hipStream_t stream) {
  (void)in_sizes; (void)n_in; (void)out_size;
  const size_t MB = 1024 * 1024;
  if (ws_size < 40 * MB) return;   // need 40MB scratch
  char* ws = (char*)d_ws;
  u16* Wqt = (u16*)(ws + 0 * MB);
  u16* Wkt = (u16*)(ws + 2 * MB);
  u16* Wvt = (u16*)(ws + 4 * MB);
  u16* Wot = (u16*)(ws + 6 * MB);
  u16* Qp  = (u16*)(ws + 8 * MB);
  u16* Kp  = (u16*)(ws + 16 * MB);
  u16* Vp  = (u16*)(ws + 24 * MB);
  u16* Op  = (u16*)(ws + 32 * MB);

  TransA ta;
  ta.W[0] = (const float*)d_in[3]; ta.Wt[0] = Wqt;
  ta.W[1] = (const float*)d_in[5]; ta.Wt[1] = Wkt;
  ta.W[2] = (const float*)d_in[7]; ta.Wt[2] = Wvt;
  ta.W[3] = (const float*)d_in[9]; ta.Wt[3] = Wot;
  hipLaunchKernelGGL(transW, dim3(16, 16, 4), dim3(256), 0, stream, ta);

  GemmB gp;
  gp.A[0] = d_in[0]; gp.Bt[0] = Wqt; gp.bias[0] = (const float*)d_in[4]; gp.C[0] = Qp;
  gp.A[1] = d_in[1]; gp.Bt[1] = Wkt; gp.bias[1] = (const float*)d_in[6]; gp.C[1] = Kp;
  gp.A[2] = d_in[2]; gp.Bt[2] = Wvt; gp.bias[2] = (const float*)d_in[8]; gp.C[2] = Vp;
  hipLaunchKernelGGL((gemm_bt<true, false>), dim3(8, 32, 3), dim3(256), 0, stream, gp);

  hipLaunchKernelGGL(attn_fwd, dim3(16, 16, 2), dim3(256), 0, stream, Qp, Kp, Vp, Op);

  GemmB gf;
  gf.A[0] = Op; gf.Bt[0] = Wot; gf.bias[0] = (const float*)d_in[10]; gf.C[0] = d_out;
  gf.A[1] = nullptr; gf.A[2] = nullptr; gf.Bt[1] = nullptr; gf.Bt[2] = nullptr;
  gf.bias[1] = nullptr; gf.bias[2] = nullptr; gf.C[1] = nullptr; gf.C[2] = nullptr;
  hipLaunchKernelGGL((gemm_bt<false, true>), dim3(8, 32, 1), dim3(256), 0, stream, gf);
}

// Round 3
// 178.986 us; speedup vs baseline: 1.3342x; 1.3342x over previous
//
#include <hip/hip_runtime.h>

typedef unsigned short u16;
typedef unsigned int   u32;
typedef __bf16 bf16x8 __attribute__((ext_vector_type(8)));
typedef float  f32x4  __attribute__((ext_vector_type(4)));

union U16B { int4 i4; bf16x8 b8; u16 u[8]; };
union U16Q { uint2 d2; u16 u[4]; };

static __device__ __forceinline__ u16 f2b(float f) {
  u32 x = __float_as_uint(f);
  x += 0x7FFFu + ((x >> 16) & 1u);   // RNE (inputs finite)
  return (u16)(x >> 16);
}
static __device__ __forceinline__ float b2f(u16 s) {
  return __uint_as_float(((u32)s) << 16);
}

// ---------------- weight transpose + fp32->bf16 convert ----------------
struct TransA { const float* W[4]; u16* Wt[4]; };

__global__ __launch_bounds__(256) void transW(TransA a) {
  const float* W  = a.W[blockIdx.z];
  u16*         Wt = a.Wt[blockIdx.z];
  __shared__ float t[64][65];
  const int bx = blockIdx.x * 64, by = blockIdx.y * 64;
  const int tx = threadIdx.x & 63, ty = threadIdx.x >> 6;
  #pragma unroll
  for (int j = 0; j < 16; ++j) {
    int row = j * 4 + ty;
    t[row][tx] = W[(size_t)(by + row) * 1024 + bx + tx];
  }
  __syncthreads();
  #pragma unroll
  for (int j = 0; j < 16; ++j) {
    int row = j * 4 + ty;           // Wt[n][k] = W[k][n]
    Wt[(size_t)(bx + row) * 1024 + by + tx] = f2b(t[tx][row]);
  }
}

// ---------------- GEMM: C = A[M][K] * Bt[N][K]^T + bias ----------------
// 128x128 tile, BK=64, 4 waves. mode: 0=bf16 row-major, 1=f32 row-major,
// 2=bf16 TRANSPOSED (C^T[N][M], M=4096) for the V projection.
struct GemmB { const void* A[3]; const u16* Bt[3]; const float* bias[3]; void* C[3]; int mode[3]; };

template<bool A_F32>
__global__ __launch_bounds__(256) void gemm_bt(GemmB g) {
  constexpr int K = 1024, N = 1024;
  __shared__ u16 As[128 * 64];
  __shared__ u16 Bs[128 * 64];
  const int z = blockIdx.z;
  const void*  Ap   = g.A[z];
  const u16*   Bt   = g.Bt[z];
  const float* bias = g.bias[z];
  const int mode = g.mode[z];
  const int tid = threadIdx.x;
  const int row0 = blockIdx.y * 128, col0 = blockIdx.x * 128;
  const int wid = tid >> 6, lane = tid & 63;
  const int wr = wid >> 1, wc = wid & 1;
  const int lo = lane & 15, hi = lane >> 4;
  const int rs = tid >> 3, us = tid & 7;

  f32x4 acc[4][4];
  const f32x4 z4 = {0.f, 0.f, 0.f, 0.f};
  #pragma unroll
  for (int i = 0; i < 4; ++i)
    #pragma unroll
    for (int j = 0; j < 4; ++j) acc[i][j] = z4;

  for (int kt = 0; kt < K / 64; ++kt) {
    __syncthreads();
    #pragma unroll
    for (int c = 0; c < 4; ++c) {
      int r = c * 32 + rs;
      int lds = r * 64 + ((us ^ (r & 7)) << 3);
      int4 av;
      if (A_F32) {
        const float* s = (const float*)Ap + (size_t)(row0 + r) * K + kt * 64 + us * 8;
        float4 f0 = *(const float4*)s;
        float4 f1 = *(const float4*)(s + 4);
        U16B t;
        t.u[0] = f2b(f0.x); t.u[1] = f2b(f0.y); t.u[2] = f2b(f0.z); t.u[3] = f2b(f0.w);
        t.u[4] = f2b(f1.x); t.u[5] = f2b(f1.y); t.u[6] = f2b(f1.z); t.u[7] = f2b(f1.w);
        av = t.i4;
      } else {
        av = *(const int4*)((const u16*)Ap + (size_t)(row0 + r) * K + kt * 64 + us * 8);
      }
      *(int4*)&As[lds] = av;
      *(int4*)&Bs[lds] = *(const int4*)(Bt + (size_t)(col0 + r) * K + kt * 64 + us * 8);
    }
    __syncthreads();
    #pragma unroll
    for (int ks = 0; ks < 2; ++ks) {
      bf16x8 af[4], bfr[4];
      #pragma unroll
      for (int mf = 0; mf < 4; ++mf) {
        int r = wr * 64 + mf * 16 + lo;
        af[mf] = *(const bf16x8*)&As[r * 64 + (((ks * 4 + hi) ^ (r & 7)) << 3)];
      }
      #pragma unroll
      for (int nf = 0; nf < 4; ++nf) {
        int r = wc * 64 + nf * 16 + lo;
        bfr[nf] = *(const bf16x8*)&Bs[r * 64 + (((ks * 4 + hi) ^ (r & 7)) << 3)];
      }
      #pragma unroll
      for (int mf = 0; mf < 4; ++mf)
        #pragma unroll
        for (int nf = 0; nf < 4; ++nf)
          acc[mf][nf] = __builtin_amdgcn_mfma_f32_16x16x32_bf16(af[mf], bfr[nf], acc[mf][nf], 0, 0, 0);
    }
  }

  #pragma unroll
  for (int nf = 0; nf < 4; ++nf) {
    int col = col0 + wc * 64 + nf * 16 + lo;
    float bv = bias[col];
    #pragma unroll
    for (int mf = 0; mf < 4; ++mf) {
      int rb = row0 + wr * 64 + mf * 16 + hi * 4;   // C/D: row=(l>>4)*4+e, col=l&15
      if (mode == 2) {
        U16Q q4;
        #pragma unroll
        for (int e = 0; e < 4; ++e) q4.u[e] = f2b(acc[mf][nf][e] + bv);
        *(uint2*)&((u16*)g.C[z])[(size_t)col * 4096 + rb] = q4.d2;   // C^T[N][4096]
      } else {
        #pragma unroll
        for (int e = 0; e < 4; ++e) {
          float v = acc[mf][nf][e] + bv;
          if (mode == 1) ((float*)g.C[z])[(size_t)(rb + e) * N + col] = v;
          else           ((u16*)g.C[z])[(size_t)(rb + e) * N + col] = f2b(v);
        }
      }
    }
  }
}

// ---------------- flash attention ----------------
// 64 q-rows/block, 4 waves x 16 rows. KBLK=64. Swapped QK^T (S^T = K*Q^T per
// MFMA semantics) so each lane owns P[q][16 kk values] -> packed b64 P writes
// + 2-shfl row reduce. V comes pre-transposed VpT[1024][4096].
// P-tile rows are PER-WAVE: row = wid*16 + lo  (round-2 bug: missing wid*16
// made all 4 waves race on rows 0..15).
__global__ __launch_bounds__(256) void attn_fwd(const u16* __restrict__ Q,
                                                const u16* __restrict__ Kp,
                                                const u16* __restrict__ VpT,
                                                u16* __restrict__ O) {
  __shared__ u16 Ks[64 * 64];    // K tile [kk][d], XOR-swizzled rows
  __shared__ u16 Vts[64 * 64];   // V^T tile [d][kk], XOR-swizzled rows
  __shared__ u16 Ps[64 * 64];    // P tile [q][kk], XOR-swizzled rows
  const int tid = threadIdx.x;
  // XCD-aware decode: xcd = bid&7 owns 4 (h,b) pairs -> K/V L2-resident
  const int bid = blockIdx.x;
  const int t = bid >> 3;
  const int hb = (bid & 7) * 4 + (t >> 5);
  const int qb = t & 31;
  const int h = hb & 15, b = hb >> 4;
  const int wid = tid >> 6, lane = tid & 63;
  const int lo = lane & 15, hi = lane >> 4;
  const int rs = tid >> 3, us = tid & 7;
  const int hoff = h * 64;
  const size_t rowQ0 = (size_t)b * 2048 + (size_t)qb * 64;
  const float QSCALE = 0.125f * 1.4426950408889634f;

  // Q fragments (B-operand): lane holds Q[q = wid*16+lo][d = ks*32 + hi*8 .. +8]
  bf16x8 qf[2];
  #pragma unroll
  for (int ks = 0; ks < 2; ++ks) {
    size_t r = rowQ0 + wid * 16 + lo;
    U16B in; in.i4 = *(const int4*)&Q[r * 1024 + hoff + ks * 32 + hi * 8];
    U16B o;
    #pragma unroll
    for (int j = 0; j < 8; ++j) o.u[j] = f2b(b2f(in.u[j]) * QSCALE);
    qf[ks] = o.b8;
  }

  f32x4 oacc[4];
  const f32x4 z4 = {0.f, 0.f, 0.f, 0.f};
  #pragma unroll
  for (int df = 0; df < 4; ++df) oacc[df] = z4;
  float m_r = -1e30f, l_r = 0.f;   // row stats for q = wid*16+lo (replicated over hi)

  for (int kb = 0; kb < 32; ++kb) {
    const int kv0 = kb * 64;
    __syncthreads();
    #pragma unroll
    for (int c = 0; c < 2; ++c) {
      int r = c * 32 + rs;
      int lds = r * 64 + ((us ^ (r & 7)) << 3);
      *(int4*)&Ks[lds]  = *(const int4*)&Kp[((size_t)b * 2048 + kv0 + r) * 1024 + hoff + us * 8];
      *(int4*)&Vts[lds] = *(const int4*)&VpT[(size_t)(hoff + r) * 4096 + b * 2048 + kv0 + us * 8];
    }
    __syncthreads();

    // S^T = K Q^T : frag nf covers kk = nf*16 + hi*4 + e, q = wid*16+lo
    f32x4 sfr[4];
    #pragma unroll
    for (int nf = 0; nf < 4; ++nf) sfr[nf] = z4;
    #pragma unroll
    for (int ks = 0; ks < 2; ++ks) {
      #pragma unroll
      for (int nf = 0; nf < 4; ++nf) {
        int kk = nf * 16 + lo;
        bf16x8 kf = *(const bf16x8*)&Ks[kk * 64 + (((ks * 4 + hi) ^ (kk & 7)) << 3)];
        sfr[nf] = __builtin_amdgcn_mfma_f32_16x16x32_bf16(kf, qf[ks], sfr[nf], 0, 0, 0);
      }
    }

    // online softmax (16 values per lane, reduce over hi via 2 shfl)
    float pm = -1e30f;
    #pragma unroll
    for (int nf = 0; nf < 4; ++nf)
      #pragma unroll
      for (int e = 0; e < 4; ++e) pm = fmaxf(pm, sfr[nf][e]);
    pm = fmaxf(pm, __shfl_xor(pm, 16));
    pm = fmaxf(pm, __shfl_xor(pm, 32));
    float mn = fmaxf(m_r, pm);
    float cc = __builtin_amdgcn_exp2f(m_r - mn);
    m_r = mn;
    float ps = 0.f;
    #pragma unroll
    for (int nf = 0; nf < 4; ++nf) {
      U16Q pk;
      #pragma unroll
      for (int e = 0; e < 4; ++e) {
        float p = __builtin_amdgcn_exp2f(sfr[nf][e] - mn);
        ps += p;
        pk.u[e] = f2b(p);
      }
      *(uint2*)&Ps[(wid * 16 + lo) * 64 + ((nf * 16 + hi * 4) ^ ((lo & 7) << 3))] = pk.d2;
    }
    ps += __shfl_xor(ps, 16);
    ps += __shfl_xor(ps, 32);
    l_r = l_r * cc + ps;
    float cce[4];
    #pragma unroll
    for (int e = 0; e < 4; ++e) cce[e] = __shfl(cc, hi * 4 + e);
    __syncthreads();

    // O = O*cc + P V
    #pragma unroll
    for (int ksp = 0; ksp < 2; ++ksp) {
      bf16x8 pa = *(const bf16x8*)&Ps[(wid * 16 + lo) * 64 + ((((ksp * 4 + hi) ^ (lo & 7))) << 3)];
      bf16x8 vb[4];
      #pragma unroll
      for (int df = 0; df < 4; ++df) {
        int d = df * 16 + lo;
        vb[df] = *(const bf16x8*)&Vts[d * 64 + (((ksp * 4 + hi) ^ (d & 7)) << 3)];
      }
      if (ksp == 0) {
        #pragma unroll
        for (int df = 0; df < 4; ++df)
          #pragma unroll
          for (int e = 0; e < 4; ++e) oacc[df][e] *= cce[e];
      }
      #pragma unroll
      for (int df = 0; df < 4; ++df)
        oacc[df] = __builtin_amdgcn_mfma_f32_16x16x32_bf16(pa, vb[df], oacc[df], 0, 0, 0);
    }
  }

  // epilogue: normalize (stats live at q=wid*16+lo; O rows are q=hi*4+e -> gather)
  float inv = __builtin_amdgcn_rcpf(l_r);
  float inve[4];
  #pragma unroll
  for (int e = 0; e < 4; ++e) inve[e] = __shfl(inv, hi * 4 + e);
  #pragma unroll
  for (int df = 0; df < 4; ++df)
    #pragma unroll
    for (int e = 0; e < 4; ++e) {
      size_t row = rowQ0 + wid * 16 + hi * 4 + e;
      O[row * 1024 + hoff + df * 16 + lo] = f2b(oacc[df][e] * inve[e]);
    }
}

// ---------------- launch ----------------
extern "C" void kernel_launch(void* const* d_in, const int* in_sizes, int n_in,
                              void* d_out, int out_size, void* d_ws, size_t ws_size,
                              hipStream_t stream) {
  (void)in_sizes; (void)n_in; (void)out_size;
  const size_t MB = 1024 * 1024;
  if (ws_size < 40 * MB) return;
  char* ws = (char*)d_ws;
  u16* Wqt = (u16*)(ws + 0 * MB);
  u16* Wkt = (u16*)(ws + 2 * MB);
  u16* Wvt = (u16*)(ws + 4 * MB);
  u16* Wot = (u16*)(ws + 6 * MB);
  u16* Qp  = (u16*)(ws + 8 * MB);
  u16* Kp  = (u16*)(ws + 16 * MB);
  u16* VpT = (u16*)(ws + 24 * MB);   // V^T [1024][4096]
  u16* Op  = (u16*)(ws + 32 * MB);

  TransA ta;
  ta.W[0] = (const float*)d_in[3]; ta.Wt[0] = Wqt;
  ta.W[1] = (const float*)d_in[5]; ta.Wt[1] = Wkt;
  ta.W[2] = (const float*)d_in[7]; ta.Wt[2] = Wvt;
  ta.W[3] = (const float*)d_in[9]; ta.Wt[3] = Wot;
  hipLaunchKernelGGL(transW, dim3(16, 16, 4), dim3(256), 0, stream, ta);

  GemmB gp;
  gp.A[0] = d_in[0]; gp.Bt[0] = Wqt; gp.bias[0] = (const float*)d_in[4]; gp.C[0] = Qp;  gp.mode[0] = 0;
  gp.A[1] = d_in[1]; gp.Bt[1] = Wkt; gp.bias[1] = (const float*)d_in[6]; gp.C[1] = Kp;  gp.mode[1] = 0;
  gp.A[2] = d_in[2]; gp.Bt[2] = Wvt; gp.bias[2] = (const float*)d_in[8]; gp.C[2] = VpT; gp.mode[2] = 2;
  hipLaunchKernelGGL((gemm_bt<true>), dim3(8, 32, 3), dim3(256), 0, stream, gp);

  hipLaunchKernelGGL(attn_fwd, dim3(1024), dim3(256), 0, stream, Qp, Kp, VpT, Op);

  GemmB gf;
  gf.A[0] = Op; gf.Bt[0] = Wot; gf.bias[0] = (const float*)d_in[10]; gf.C[0] = d_out; gf.mode[0] = 1;
  gf.A[1] = nullptr; gf.A[2] = nullptr; gf.Bt[1] = nullptr; gf.Bt[2] = nullptr;
  gf.bias[1] = nullptr; gf.bias[2] = nullptr; gf.C[1] = nullptr; gf.C[2] = nullptr;
  gf.mode[1] = 0; gf.mode[2] = 0;
  hipLaunchKernelGGL((gemm_bt<false>), dim3(8, 32, 1), dim3(256), 0, stream, gf);
}